// Round 10
// baseline (188.017 us; speedup 1.0000x reference)
//
#include <hip/hip_runtime.h>

#define EPS 1e-5f

typedef __attribute__((ext_vector_type(8))) short short8;
typedef __attribute__((ext_vector_type(4))) float float4v;

__device__ inline unsigned short f2bf(float f) {
  unsigned u = __float_as_uint(f);
  unsigned r = (u + 0x7fffu + ((u >> 16) & 1u)) >> 16;
  return (unsigned short)r;
}
__device__ inline uint pk2(float a, float b) {
  return (uint)f2bf(a) | ((uint)f2bf(b) << 16);
}

// ---------------------------------------------------------------------------
// INSTRUMENTATION ROUND v2 (re-run after infra failure): compress and encode
// run 4x redundant idempotent work (duplicate blocks recompute and rewrite
// identical values) so both cross the ~43us fill threshold and surface in
// the rocprof top-5 with real counters. True cost = visible dur / 4.
// carafe/xform are R8-exact (carafe already characterized in R7).
// Revert the duplication next round.
// ---------------------------------------------------------------------------

// ---------------------------------------------------------------------------
// xform: fold BN scale into weights + both bias vectors. (R5 exact)
// ---------------------------------------------------------------------------
__global__ __launch_bounds__(256) void xform_kernel(
    const float* __restrict__ enc_w, const float* __restrict__ enc_gamma,
    const float* __restrict__ enc_var, const float* __restrict__ comp_w,
    const float* __restrict__ comp_gamma, const float* __restrict__ comp_var,
    const float* __restrict__ enc_b, const float* __restrict__ enc_beta,
    const float* __restrict__ enc_mean, const float* __restrict__ comp_beta,
    const float* __restrict__ comp_mean, ushort* __restrict__ Awt,
    float* __restrict__ Wc, float* __restrict__ bias2,
    float* __restrict__ bias_c) {
  int u = blockIdx.x * 256 + threadIdx.x;
  if (u < 9216) {
    int kc = u >> 9, rem = u & 511;
    int mt = rem >> 6, q = (rem >> 4) & 3, ml = rem & 15;
    int e = mt * 16 + ml;
    int t = kc >> 1, h = kc & 1;
    int dy = t / 3, dx = t - dy * 3;
    float inv = (e < 100) ? enc_gamma[e] * rsqrtf(enc_var[e] + EPS) : 0.f;
    ushort o[8];
#pragma unroll
    for (int j = 0; j < 8; ++j) {
      int ci = h * 32 + q * 8 + j;
      float w = (e < 100) ? enc_w[(e * 64 + ci) * 9 + dy * 3 + dx] * inv : 0.f;
      o[j] = f2bf(w);
    }
    uint4 v;
    v.x = (uint)o[0] | ((uint)o[1] << 16);
    v.y = (uint)o[2] | ((uint)o[3] << 16);
    v.z = (uint)o[4] | ((uint)o[5] << 16);
    v.w = (uint)o[6] | ((uint)o[7] << 16);
    *reinterpret_cast<uint4*>(Awt + (size_t)u * 8) = v;
  } else if (u < 13312) {
    int v = u - 9216;
    int co = v & 63;
    float inv = comp_gamma[co] * rsqrtf(comp_var[co] + EPS);
    Wc[v] = comp_w[co * 64 + (v >> 6)] * inv;
  } else if (u < 13440) {
    int t = u - 13312;
    float v = 0.f;
    if (t < 100) {
      float inv = enc_gamma[t] * rsqrtf(enc_var[t] + EPS);
      v = enc_b[t] * inv + enc_beta[t] - enc_mean[t] * inv;
    }
    bias2[t] = v;
  } else if (u < 13504) {
    int c = u - 13440;
    float inv = comp_gamma[c] * rsqrtf(comp_var[c] + EPS);
    bias_c[c] = comp_beta[c] - comp_mean[c] * inv;
  }
}

// ---------------------------------------------------------------------------
// compress: 1x1 conv 64->64 + BN + ReLU -> Wm1t + Xb (bf16 pixel-major).
// (R5 code; PROBE: grid 1024->4096, blockIdx.x & 1023 -> 4x redundant)
// ---------------------------------------------------------------------------
__global__ __launch_bounds__(256) void compress_kernel(
    const float* __restrict__ X, const float* __restrict__ Wc,
    const float* __restrict__ bias_c, ushort* __restrict__ out,
    ushort* __restrict__ Xb) {
  __shared__ __align__(16) float xtile[64 * 65];
  __shared__ __align__(16) float osm[64 * 68];
  const int tid = threadIdx.x;
  const int p0 = (blockIdx.x & 1023) * 64;
  const int b = p0 >> 14;
  const float* xbase = X + ((size_t)b << 20) + (p0 & 16383);

#pragma unroll
  for (int k = 0; k < 16; ++k) {
    int u = k * 256 + tid;
    int ci = u >> 6, px = u & 63;      // wave: ci fixed, px 0..63 -> coalesced
    xtile[px * 65 + ci] = xbase[((size_t)ci << 14) + px];
  }
  __syncthreads();

  const int wv = __builtin_amdgcn_readfirstlane(tid >> 6);
  const int ln = tid & 63;
  float acc[16];
#pragma unroll
  for (int u = 0; u < 16; ++u) acc[u] = bias_c[wv * 16 + u];
  const float* xr = xtile + ln * 65;
#pragma unroll 8
  for (int ci = 0; ci < 64; ++ci) {
    float xv = xr[ci];
    const float* wr = Wc + ci * 64 + wv * 16;   // wave-uniform -> s_load
#pragma unroll
    for (int u = 0; u < 16; ++u) acc[u] = fmaf(wr[u], xv, acc[u]);
  }
  float4v* orow = reinterpret_cast<float4v*>(osm) + ln * 17 + wv * 4;
#pragma unroll
  for (int j = 0; j < 4; ++j) {
    float4v t;
#pragma unroll
    for (int s = 0; s < 4; ++s) t[s] = fmaxf(acc[j * 4 + s], 0.f);
    orow[j] = t;                        // stride-17 float4 -> conflict-free
  }
  __syncthreads();

#pragma unroll
  for (int j = 0; j < 2; ++j) {
    int u = j * 256 + tid;
    int px = u >> 3, g = u & 7;
    const float* so = osm + px * 68 + g * 8;
    uint4 vo = make_uint4(pk2(so[0], so[1]), pk2(so[2], so[3]),
                          pk2(so[4], so[5]), pk2(so[6], so[7]));
    *reinterpret_cast<uint4*>(out + (size_t)(p0 + px) * 64 + g * 8) = vo;
    const float* sx = xtile + px * 65 + g * 8;
    uint4 vx = make_uint4(pk2(sx[0], sx[1]), pk2(sx[2], sx[3]),
                          pk2(sx[4], sx[5]), pk2(sx[6], sx[7]));
    *reinterpret_cast<uint4*>(Xb + (size_t)(p0 + px) * 64 + g * 8) = vx;
  }
}

// ---------------------------------------------------------------------------
// encode: 3x3 conv (64->100) implicit GEMM on MFMA + bias + softmax(25) +
// pixel-shuffle de-interleave + bf16 pack -> tile-major Wtu.
// (R5 code; PROBE: grid z 4->16, b = blockIdx.z & 3 -> 4x redundant)
// ---------------------------------------------------------------------------
__global__ __launch_bounds__(256) void encode_mfma(
    const ushort* __restrict__ Wm1t, const ushort* __restrict__ Awt,
    const float* __restrict__ bias2, uint* __restrict__ Wtu) {
  __shared__ __align__(16) char smem[25856];   // Xt 14400 -> wsm 25856 -> wpT
  ushort* Xt = (ushort*)smem;                  // [100 pos (10x10)][72 ci]
  const int tid = threadIdx.x;
  const int b = blockIdx.z & 3;
  const int y0 = blockIdx.y * 8, x0 = blockIdx.x * 8;

  // ---- phase 1: stage compressed features (10x10 halo) ----
  for (int u = tid; u < 800; u += 256) {       // 100 pos x 8 ci-groups
    int pos = u >> 3, cg = u & 7;
    int iy = pos / 10, ix = pos - iy * 10;
    int gy = y0 + iy - 1, gx = x0 + ix - 1;
    uint4 v = make_uint4(0, 0, 0, 0);
    if ((unsigned)gy < 128u && (unsigned)gx < 128u)
      v = *reinterpret_cast<const uint4*>(
          Wm1t + ((((size_t)b << 14) + (gy << 7) + gx) << 6) + cg * 8);
    *reinterpret_cast<uint4*>(&Xt[pos * 72 + cg * 8]) = v;
  }
  __syncthreads();

  // ---- phase 2: implicit-GEMM MFMA over 18 kc slices ----
  const int wave = tid >> 6, lane = tid & 63;
  const int q = lane >> 4, px16 = lane & 15;

  float4v acc[2][4];
#pragma unroll
  for (int a = 0; a < 2; ++a)
#pragma unroll
    for (int n = 0; n < 4; ++n) acc[a][n] = (float4v){0.f, 0.f, 0.f, 0.f};

  const short8* Ap = reinterpret_cast<const short8*>(Awt);
#pragma unroll
  for (int kc = 0; kc < 18; ++kc) {
    const int t = kc >> 1, h = kc & 1;
    const int dy = t / 3, dx = t - dy * 3;
    short8 af[2];
#pragma unroll
    for (int a = 0; a < 2; ++a)
      af[a] = Ap[kc * 512 + (wave * 2 + a) * 64 + lane];
    short8 bfr[4];
#pragma unroll
    for (int n = 0; n < 4; ++n) {
      int p = n * 16 + px16;                  // pixel in 8x8 tile, row-major 8
      int iy = (p >> 3) + dy, ix = (p & 7) + dx;
      bfr[n] = *reinterpret_cast<const short8*>(
          &Xt[(iy * 10 + ix) * 72 + h * 32 + q * 8]);
    }
#pragma unroll
    for (int a = 0; a < 2; ++a)
#pragma unroll
      for (int n = 0; n < 4; ++n)
        acc[a][n] = __builtin_amdgcn_mfma_f32_16x16x32_bf16(
            af[a], bfr[n], acc[a][n], 0, 0, 0);
  }
  __syncthreads();

  // ---- phase 3: accumulators -> wsm [64 px][101] (stride 101 === 5 mod 32,
  // coprime -> phase-4 reads conflict-free; b32 stores) ----
  float* wsm = (float*)smem;
#pragma unroll
  for (int a = 0; a < 2; ++a) {
    int ebase = (wave * 2 + a) * 16 + q * 4;
    if (ebase < 100) {
#pragma unroll
      for (int n = 0; n < 4; ++n) {
        int p = n * 16 + px16;
        float* dst = wsm + p * 101 + ebase;
        dst[0] = acc[a][n][0];
        dst[1] = acc[a][n][1];
        dst[2] = acc[a][n][2];
        dst[3] = acc[a][n][3];
      }
    }
  }
  __syncthreads();

  // ---- phase 4: bias + softmax(25), one (pixel, component) per thread ----
  {
    const int px = tid & 63, qd = tid >> 6;
    const int rowbase = (qd >> 1) * 28;
    const int half = qd & 1;
    const float* wp = wsm + px * 101 + qd;
    float v[25];
#pragma unroll
    for (int j = 0; j < 25; ++j) v[j] = wp[4 * j] + bias2[4 * j + qd];
    float m = v[0];
#pragma unroll
    for (int j = 1; j < 25; ++j) m = fmaxf(m, v[j]);
    float s = 0.f;
#pragma unroll
    for (int j = 0; j < 25; ++j) { v[j] = __expf(v[j] - m); s += v[j]; }
    float inv = 1.f / s;
    __syncthreads();                           // wsm now dead -> reuse as wpT
    ushort* wpS = (ushort*)smem;               // ushort view of wpT [56][128]
#pragma unroll
    for (int k = 0; k < 25; ++k)
      wpS[(rowbase + k) * 128 + px * 2 + half] = f2bf(v[k] * inv);
  }
  __syncthreads();

  // ---- phase 5: stream wpT out, tile-major + coalesced ----
  {
    const uint4* src = (const uint4*)smem;     // wpT [56][64] uint = 896 uint4
    uint4* dst = reinterpret_cast<uint4*>(
        Wtu + (size_t)((b * 16 + blockIdx.y) * 16 + blockIdx.x) * 3584);
    for (int u = tid; u < 896; u += 256) dst[u] = src[u];
  }
}

// ---------------------------------------------------------------------------
// carafe v3 (R8 exact, unduplicated)
// ---------------------------------------------------------------------------
__global__ __launch_bounds__(256) void carafe_kernel(
    const ushort* __restrict__ Xb, const uint* __restrict__ Wtu,
    float* __restrict__ out) {
  const int tid = threadIdx.x;
  const int b = blockIdx.z;
  const int y0 = blockIdx.y * 8, x0 = blockIdx.x * 8;
  __shared__ __align__(16) ushort xt[144 * 72];

  for (int u = tid; u < 1152; u += 256) {      // 144 pos x 8 ch-groups
    int pos = u >> 3, cg = u & 7;
    int iy = pos / 12, ix = pos - iy * 12;
    int gy = y0 + iy - 2, gx = x0 + ix - 2;
    uint4 v = make_uint4(0, 0, 0, 0);
    if ((unsigned)gy < 128u && (unsigned)gx < 128u)
      v = *reinterpret_cast<const uint4*>(
          Xb + (((size_t)b * 16384 + gy * 128 + gx) << 6) + cg * 8);
    *reinterpret_cast<uint4*>(&xt[pos * 72 + cg * 8]) = v;
  }
  __syncthreads();

  const int p = tid & 63, cg2 = tid >> 6;      // 16 channels per thread
  const int py = p >> 3, px = p & 7;

  const uint* wt = Wtu +
      (size_t)((b * 16 + blockIdx.y) * 16 + blockIdx.x) * 3584 + p;

  float2 a0[16], a1[16];                       // [ch] x (xq, xq+1), r1=0/1
#pragma unroll
  for (int i = 0; i < 16; ++i) {
    a0[i] = make_float2(0.f, 0.f);
    a1[i] = make_float2(0.f, 0.f);
  }

#pragma unroll
  for (int k = 0; k < 25; ++k) {
    const int dy = k / 5, dx = k - dy * 5;
    const ushort* bp = xt + ((py + dy) * 12 + (px + dx)) * 72 + cg2 * 16;
    uint wk0 = wt[k * 64];                     // r1=0 weights (comp0, comp1)
    uint wk1 = wt[(28 + k) * 64];              // r1=1 weights (comp2, comp3)
    float w00 = __uint_as_float(wk0 << 16);
    float w01 = __uint_as_float(wk0 & 0xffff0000u);
    float w10 = __uint_as_float(wk1 << 16);
    float w11 = __uint_as_float(wk1 & 0xffff0000u);
#pragma unroll
    for (int j = 0; j < 2; ++j) {
      uint4 xv = *reinterpret_cast<const uint4*>(bp + 8 * j);
      const uint xu[4] = {xv.x, xv.y, xv.z, xv.w};
#pragma unroll
      for (int t = 0; t < 4; ++t) {
        float xlo = __uint_as_float(xu[t] << 16);
        float xhi = __uint_as_float(xu[t] & 0xffff0000u);
        int c = j * 8 + t * 2;
        a0[c].x = fmaf(w00, xlo, a0[c].x);
        a0[c].y = fmaf(w01, xlo, a0[c].y);
        a1[c].x = fmaf(w10, xlo, a1[c].x);
        a1[c].y = fmaf(w11, xlo, a1[c].y);
        a0[c + 1].x = fmaf(w00, xhi, a0[c + 1].x);
        a0[c + 1].y = fmaf(w01, xhi, a0[c + 1].y);
        a1[c + 1].x = fmaf(w10, xhi, a1[c + 1].x);
        a1[c + 1].y = fmaf(w11, xhi, a1[c + 1].y);
      }
    }
  }

  const int yq0 = (y0 + py) * 2;
  const int xq = (x0 + px) * 2;
#pragma unroll
  for (int ci = 0; ci < 16; ++ci) {
    int c = cg2 * 16 + ci;
    float* o = out + ((size_t)(b * 64 + c) * 256 + yq0) * 256 + xq;
    *reinterpret_cast<float2*>(o) = a0[ci];        // row yq0   (r1=0)
    *reinterpret_cast<float2*>(o + 256) = a1[ci];  // row yq0+1 (r1=1)
  }
}

// ---------------------------------------------------------------------------
extern "C" void kernel_launch(void* const* d_in, const int* in_sizes, int n_in,
                              void* d_out, int out_size, void* d_ws, size_t ws_size,
                              hipStream_t stream) {
  const float* X          = (const float*)d_in[0];
  const float* comp_w     = (const float*)d_in[1];
  const float* comp_gamma = (const float*)d_in[2];
  const float* comp_beta  = (const float*)d_in[3];
  const float* comp_mean  = (const float*)d_in[4];
  const float* comp_var   = (const float*)d_in[5];
  const float* enc_w      = (const float*)d_in[6];
  const float* enc_b      = (const float*)d_in[7];
  const float* enc_gamma  = (const float*)d_in[8];
  const float* enc_beta   = (const float*)d_in[9];
  const float* enc_mean   = (const float*)d_in[10];
  const float* enc_var    = (const float*)d_in[11];
  float* out = (float*)d_out;

  char* ws = (char*)d_ws;
  ushort* Wm1t  = (ushort*)(ws);                    //  8,388,608 B
  uint*   Wtu   = (uint*)(ws + 8388608);            // 14,680,064 B (tile-major)
  ushort* Xb    = (ushort*)(ws + 23068672);         //  8,388,608 B
  ushort* Awt   = (ushort*)(ws + 31457280);         //    147,456 B
  float*  Wc    = (float*)(ws + 31604736);          //     16,384 B
  float*  bias2 = (float*)(ws + 31621120);          //        512 B
  float*  biasc = (float*)(ws + 31621632);          //        256 B

  xform_kernel<<<53, 256, 0, stream>>>(enc_w, enc_gamma, enc_var,
                                       comp_w, comp_gamma, comp_var,
                                       enc_b, enc_beta, enc_mean,
                                       comp_beta, comp_mean,
                                       Awt, Wc, bias2, biasc);
  compress_kernel<<<4096, 256, 0, stream>>>(X, Wc, biasc, Wm1t, Xb);
  encode_mfma<<<dim3(16, 16, 16), 256, 0, stream>>>(Wm1t, Awt, bias2, Wtu);
  carafe_kernel<<<dim3(16, 16, 4), 256, 0, stream>>>(Xb, Wtu, out);
}

// Round 11
// 145.891 us; speedup vs baseline: 1.2887x; 1.2887x over previous
//
#include <hip/hip_runtime.h>

#define EPS 1e-5f

typedef __attribute__((ext_vector_type(8))) short short8;
typedef __attribute__((ext_vector_type(4))) float float4v;

__device__ inline unsigned short f2bf(float f) {
  unsigned u = __float_as_uint(f);
  unsigned r = (u + 0x7fffu + ((u >> 16) & 1u)) >> 16;
  return (unsigned short)r;
}
__device__ inline uint pk2(float a, float b) {
  return (uint)f2bf(a) | ((uint)f2bf(b) << 16);
}

// ---------------------------------------------------------------------------
// Measured budget (R10 4x-duplication probe): xform ~3us, compress ~5us,
// encode ~13us (VGPR=56, MfmaUtil 30%, Occ 34%), carafe ~24us. ~96us of the
// 141us window is harness-side (poison fills + gaps). This round: carafe v4
// (16x4 tile, full-line writes, reg-capped 128); everything else R8-exact.
// ---------------------------------------------------------------------------

// ---------------------------------------------------------------------------
// xform: fold BN scale into weights + both bias vectors. (R5 exact)
// ---------------------------------------------------------------------------
__global__ __launch_bounds__(256) void xform_kernel(
    const float* __restrict__ enc_w, const float* __restrict__ enc_gamma,
    const float* __restrict__ enc_var, const float* __restrict__ comp_w,
    const float* __restrict__ comp_gamma, const float* __restrict__ comp_var,
    const float* __restrict__ enc_b, const float* __restrict__ enc_beta,
    const float* __restrict__ enc_mean, const float* __restrict__ comp_beta,
    const float* __restrict__ comp_mean, ushort* __restrict__ Awt,
    float* __restrict__ Wc, float* __restrict__ bias2,
    float* __restrict__ bias_c) {
  int u = blockIdx.x * 256 + threadIdx.x;
  if (u < 9216) {
    int kc = u >> 9, rem = u & 511;
    int mt = rem >> 6, q = (rem >> 4) & 3, ml = rem & 15;
    int e = mt * 16 + ml;
    int t = kc >> 1, h = kc & 1;
    int dy = t / 3, dx = t - dy * 3;
    float inv = (e < 100) ? enc_gamma[e] * rsqrtf(enc_var[e] + EPS) : 0.f;
    ushort o[8];
#pragma unroll
    for (int j = 0; j < 8; ++j) {
      int ci = h * 32 + q * 8 + j;
      float w = (e < 100) ? enc_w[(e * 64 + ci) * 9 + dy * 3 + dx] * inv : 0.f;
      o[j] = f2bf(w);
    }
    uint4 v;
    v.x = (uint)o[0] | ((uint)o[1] << 16);
    v.y = (uint)o[2] | ((uint)o[3] << 16);
    v.z = (uint)o[4] | ((uint)o[5] << 16);
    v.w = (uint)o[6] | ((uint)o[7] << 16);
    *reinterpret_cast<uint4*>(Awt + (size_t)u * 8) = v;
  } else if (u < 13312) {
    int v = u - 9216;
    int co = v & 63;
    float inv = comp_gamma[co] * rsqrtf(comp_var[co] + EPS);
    Wc[v] = comp_w[co * 64 + (v >> 6)] * inv;
  } else if (u < 13440) {
    int t = u - 13312;
    float v = 0.f;
    if (t < 100) {
      float inv = enc_gamma[t] * rsqrtf(enc_var[t] + EPS);
      v = enc_b[t] * inv + enc_beta[t] - enc_mean[t] * inv;
    }
    bias2[t] = v;
  } else if (u < 13504) {
    int c = u - 13440;
    float inv = comp_gamma[c] * rsqrtf(comp_var[c] + EPS);
    bias_c[c] = comp_beta[c] - comp_mean[c] * inv;
  }
}

// ---------------------------------------------------------------------------
// compress: 1x1 conv 64->64 + BN + ReLU -> Wm1t + Xb (bf16 pixel-major).
// (R5 exact; probe duplication reverted)
// ---------------------------------------------------------------------------
__global__ __launch_bounds__(256) void compress_kernel(
    const float* __restrict__ X, const float* __restrict__ Wc,
    const float* __restrict__ bias_c, ushort* __restrict__ out,
    ushort* __restrict__ Xb) {
  __shared__ __align__(16) float xtile[64 * 65];
  __shared__ __align__(16) float osm[64 * 68];
  const int tid = threadIdx.x;
  const int p0 = blockIdx.x * 64;
  const int b = p0 >> 14;
  const float* xbase = X + ((size_t)b << 20) + (p0 & 16383);

#pragma unroll
  for (int k = 0; k < 16; ++k) {
    int u = k * 256 + tid;
    int ci = u >> 6, px = u & 63;      // wave: ci fixed, px 0..63 -> coalesced
    xtile[px * 65 + ci] = xbase[((size_t)ci << 14) + px];
  }
  __syncthreads();

  const int wv = __builtin_amdgcn_readfirstlane(tid >> 6);
  const int ln = tid & 63;
  float acc[16];
#pragma unroll
  for (int u = 0; u < 16; ++u) acc[u] = bias_c[wv * 16 + u];
  const float* xr = xtile + ln * 65;
#pragma unroll 8
  for (int ci = 0; ci < 64; ++ci) {
    float xv = xr[ci];
    const float* wr = Wc + ci * 64 + wv * 16;   // wave-uniform -> s_load
#pragma unroll
    for (int u = 0; u < 16; ++u) acc[u] = fmaf(wr[u], xv, acc[u]);
  }
  float4v* orow = reinterpret_cast<float4v*>(osm) + ln * 17 + wv * 4;
#pragma unroll
  for (int j = 0; j < 4; ++j) {
    float4v t;
#pragma unroll
    for (int s = 0; s < 4; ++s) t[s] = fmaxf(acc[j * 4 + s], 0.f);
    orow[j] = t;                        // stride-17 float4 -> conflict-free
  }
  __syncthreads();

#pragma unroll
  for (int j = 0; j < 2; ++j) {
    int u = j * 256 + tid;
    int px = u >> 3, g = u & 7;
    const float* so = osm + px * 68 + g * 8;
    uint4 vo = make_uint4(pk2(so[0], so[1]), pk2(so[2], so[3]),
                          pk2(so[4], so[5]), pk2(so[6], so[7]));
    *reinterpret_cast<uint4*>(out + (size_t)(p0 + px) * 64 + g * 8) = vo;
    const float* sx = xtile + px * 65 + g * 8;
    uint4 vx = make_uint4(pk2(sx[0], sx[1]), pk2(sx[2], sx[3]),
                          pk2(sx[4], sx[5]), pk2(sx[6], sx[7]));
    *reinterpret_cast<uint4*>(Xb + (size_t)(p0 + px) * 64 + g * 8) = vx;
  }
}

// ---------------------------------------------------------------------------
// encode: 3x3 conv (64->100) implicit GEMM on MFMA + bias + softmax(25) +
// pixel-shuffle de-interleave + bf16 pack -> tile-major Wtu.
// (R5 exact; probe duplication reverted. Measured: 13us, VGPR=56.)
// ---------------------------------------------------------------------------
__global__ __launch_bounds__(256) void encode_mfma(
    const ushort* __restrict__ Wm1t, const ushort* __restrict__ Awt,
    const float* __restrict__ bias2, uint* __restrict__ Wtu) {
  __shared__ __align__(16) char smem[25856];   // Xt 14400 -> wsm 25856 -> wpT
  ushort* Xt = (ushort*)smem;                  // [100 pos (10x10)][72 ci]
  const int tid = threadIdx.x;
  const int b = blockIdx.z;
  const int y0 = blockIdx.y * 8, x0 = blockIdx.x * 8;

  // ---- phase 1: stage compressed features (10x10 halo) ----
  for (int u = tid; u < 800; u += 256) {       // 100 pos x 8 ci-groups
    int pos = u >> 3, cg = u & 7;
    int iy = pos / 10, ix = pos - iy * 10;
    int gy = y0 + iy - 1, gx = x0 + ix - 1;
    uint4 v = make_uint4(0, 0, 0, 0);
    if ((unsigned)gy < 128u && (unsigned)gx < 128u)
      v = *reinterpret_cast<const uint4*>(
          Wm1t + ((((size_t)b << 14) + (gy << 7) + gx) << 6) + cg * 8);
    *reinterpret_cast<uint4*>(&Xt[pos * 72 + cg * 8]) = v;
  }
  __syncthreads();

  // ---- phase 2: implicit-GEMM MFMA over 18 kc slices ----
  const int wave = tid >> 6, lane = tid & 63;
  const int q = lane >> 4, px16 = lane & 15;

  float4v acc[2][4];
#pragma unroll
  for (int a = 0; a < 2; ++a)
#pragma unroll
    for (int n = 0; n < 4; ++n) acc[a][n] = (float4v){0.f, 0.f, 0.f, 0.f};

  const short8* Ap = reinterpret_cast<const short8*>(Awt);
#pragma unroll
  for (int kc = 0; kc < 18; ++kc) {
    const int t = kc >> 1, h = kc & 1;
    const int dy = t / 3, dx = t - dy * 3;
    short8 af[2];
#pragma unroll
    for (int a = 0; a < 2; ++a)
      af[a] = Ap[kc * 512 + (wave * 2 + a) * 64 + lane];
    short8 bfr[4];
#pragma unroll
    for (int n = 0; n < 4; ++n) {
      int p = n * 16 + px16;                  // pixel in 8x8 tile, row-major 8
      int iy = (p >> 3) + dy, ix = (p & 7) + dx;
      bfr[n] = *reinterpret_cast<const short8*>(
          &Xt[(iy * 10 + ix) * 72 + h * 32 + q * 8]);
    }
#pragma unroll
    for (int a = 0; a < 2; ++a)
#pragma unroll
      for (int n = 0; n < 4; ++n)
        acc[a][n] = __builtin_amdgcn_mfma_f32_16x16x32_bf16(
            af[a], bfr[n], acc[a][n], 0, 0, 0);
  }
  __syncthreads();

  // ---- phase 3: accumulators -> wsm [64 px][101] (stride 101 === 5 mod 32,
  // coprime -> phase-4 reads conflict-free; b32 stores) ----
  float* wsm = (float*)smem;
#pragma unroll
  for (int a = 0; a < 2; ++a) {
    int ebase = (wave * 2 + a) * 16 + q * 4;
    if (ebase < 100) {
#pragma unroll
      for (int n = 0; n < 4; ++n) {
        int p = n * 16 + px16;
        float* dst = wsm + p * 101 + ebase;
        dst[0] = acc[a][n][0];
        dst[1] = acc[a][n][1];
        dst[2] = acc[a][n][2];
        dst[3] = acc[a][n][3];
      }
    }
  }
  __syncthreads();

  // ---- phase 4: bias + softmax(25), one (pixel, component) per thread ----
  {
    const int px = tid & 63, qd = tid >> 6;
    const int rowbase = (qd >> 1) * 28;
    const int half = qd & 1;
    const float* wp = wsm + px * 101 + qd;
    float v[25];
#pragma unroll
    for (int j = 0; j < 25; ++j) v[j] = wp[4 * j] + bias2[4 * j + qd];
    float m = v[0];
#pragma unroll
    for (int j = 1; j < 25; ++j) m = fmaxf(m, v[j]);
    float s = 0.f;
#pragma unroll
    for (int j = 0; j < 25; ++j) { v[j] = __expf(v[j] - m); s += v[j]; }
    float inv = 1.f / s;
    __syncthreads();                           // wsm now dead -> reuse as wpT
    ushort* wpS = (ushort*)smem;               // ushort view of wpT [56][128]
#pragma unroll
    for (int k = 0; k < 25; ++k)
      wpS[(rowbase + k) * 128 + px * 2 + half] = f2bf(v[k] * inv);
  }
  __syncthreads();

  // ---- phase 5: stream wpT out, tile-major + coalesced ----
  {
    const uint4* src = (const uint4*)smem;     // wpT [56][64] uint = 896 uint4
    uint4* dst = reinterpret_cast<uint4*>(
        Wtu + (size_t)((b * 16 + blockIdx.y) * 16 + blockIdx.x) * 3584);
    for (int u = tid; u < 896; u += 256) dst[u] = src[u];
  }
}

// ---------------------------------------------------------------------------
// carafe v4: 16x4 lo-res tile, 512 threads, full-line stores.
//  - v3 (8x8 tile) wrote 64 B half-lines for all 67 MB of output; v4's
//    16-wide tile makes each 16-lane group write 128 B full lines on both
//    output rows. Wave-level Wtu reads also become one 128 B line per
//    encode tile per tap.
//  - thread (p, cg): pixel p (py=p>>4, px=p&15), 8 channels; computes BOTH
//    r1 rows (keeps v3's dedup: each staged value feeds 4 FMAs).
//  - acc = 32 floats (~70 live). __launch_bounds__(512, 2): allocator-model
//    cap = 256/2 = 128 regs (R2/R4/R6/R7-consistent) -> spill-free,
//    2 blocks/CU = 16 waves/CU (v3 was likely 256 VGPR / 8 waves).
//  - FMA chain per output unchanged (k ascending) -> bit-identical.
// LDS: xt [160 pos (20x8)][72 ch] bf16 = 23,040 B.
// ---------------------------------------------------------------------------
__global__ __launch_bounds__(512, 2) void carafe_kernel(
    const ushort* __restrict__ Xb, const uint* __restrict__ Wtu,
    float* __restrict__ out) {
  const int tid = threadIdx.x;
  const int b = blockIdx.z;
  const int y0 = blockIdx.y * 4, x0 = blockIdx.x * 16;
  __shared__ __align__(16) ushort xt[160 * 72];

  for (int u = tid; u < 1280; u += 512) {      // 160 pos x 8 ch-groups
    int pos = u >> 3, cg = u & 7;
    int iy = pos / 20, ix = pos - iy * 20;
    int gy = y0 + iy - 2, gx = x0 + ix - 2;
    uint4 v = make_uint4(0, 0, 0, 0);
    if ((unsigned)gy < 128u && (unsigned)gx < 128u)
      v = *reinterpret_cast<const uint4*>(
          Xb + (((size_t)b * 16384 + gy * 128 + gx) << 6) + cg * 8);
    *reinterpret_cast<uint4*>(&xt[pos * 72 + cg * 8]) = v;
  }
  __syncthreads();

  const int p = tid & 63, cg = tid >> 6;       // 8 channels per thread
  const int py = p >> 4, px = p & 15;          // 16x4 tile position

  // encode tile of this pixel + pixel-in-tile (8x8 encode tiling)
  const int tile = (b * 16 + (blockIdx.y >> 1)) * 16 + blockIdx.x * 2 + (px >> 3);
  const int pit = ((blockIdx.y & 1) * 4 + py) * 8 + (px & 7);
  const uint* wt = Wtu + (size_t)tile * 3584 + pit;

  float2 a0[8], a1[8];                         // [ch] x (xq, xq+1), r1=0/1
#pragma unroll
  for (int i = 0; i < 8; ++i) {
    a0[i] = make_float2(0.f, 0.f);
    a1[i] = make_float2(0.f, 0.f);
  }

#pragma unroll
  for (int k = 0; k < 25; ++k) {
    const int dy = k / 5, dx = k - dy * 5;
    const ushort* bp = xt + ((py + dy) * 20 + (px + dx)) * 72 + cg * 8;
    uint wk0 = wt[k * 64];                     // r1=0 weights (comp0, comp1)
    uint wk1 = wt[(28 + k) * 64];              // r1=1 weights (comp2, comp3)
    float w00 = __uint_as_float(wk0 << 16);
    float w01 = __uint_as_float(wk0 & 0xffff0000u);
    float w10 = __uint_as_float(wk1 << 16);
    float w11 = __uint_as_float(wk1 & 0xffff0000u);
    uint4 xv = *reinterpret_cast<const uint4*>(bp);
    const uint xu[4] = {xv.x, xv.y, xv.z, xv.w};
#pragma unroll
    for (int t = 0; t < 4; ++t) {
      float xlo = __uint_as_float(xu[t] << 16);
      float xhi = __uint_as_float(xu[t] & 0xffff0000u);
      int c = t * 2;
      a0[c].x = fmaf(w00, xlo, a0[c].x);
      a0[c].y = fmaf(w01, xlo, a0[c].y);
      a1[c].x = fmaf(w10, xlo, a1[c].x);
      a1[c].y = fmaf(w11, xlo, a1[c].y);
      a0[c + 1].x = fmaf(w00, xhi, a0[c + 1].x);
      a0[c + 1].y = fmaf(w01, xhi, a0[c + 1].y);
      a1[c + 1].x = fmaf(w10, xhi, a1[c + 1].x);
      a1[c + 1].y = fmaf(w11, xhi, a1[c + 1].y);
    }
  }

  const int yq0 = (y0 + py) * 2;
  const int xq = (x0 + px) * 2;
#pragma unroll
  for (int ci = 0; ci < 8; ++ci) {
    int c = cg * 8 + ci;
    float* o = out + ((size_t)(b * 64 + c) * 256 + yq0) * 256 + xq;
    *reinterpret_cast<float2*>(o) = a0[ci];        // row yq0   (r1=0)
    *reinterpret_cast<float2*>(o + 256) = a1[ci];  // row yq0+1 (r1=1)
  }
}

// ---------------------------------------------------------------------------
extern "C" void kernel_launch(void* const* d_in, const int* in_sizes, int n_in,
                              void* d_out, int out_size, void* d_ws, size_t ws_size,
                              hipStream_t stream) {
  const float* X          = (const float*)d_in[0];
  const float* comp_w     = (const float*)d_in[1];
  const float* comp_gamma = (const float*)d_in[2];
  const float* comp_beta  = (const float*)d_in[3];
  const float* comp_mean  = (const float*)d_in[4];
  const float* comp_var   = (const float*)d_in[5];
  const float* enc_w      = (const float*)d_in[6];
  const float* enc_b      = (const float*)d_in[7];
  const float* enc_gamma  = (const float*)d_in[8];
  const float* enc_beta   = (const float*)d_in[9];
  const float* enc_mean   = (const float*)d_in[10];
  const float* enc_var    = (const float*)d_in[11];
  float* out = (float*)d_out;

  char* ws = (char*)d_ws;
  ushort* Wm1t  = (ushort*)(ws);                    //  8,388,608 B
  uint*   Wtu   = (uint*)(ws + 8388608);            // 14,680,064 B (tile-major)
  ushort* Xb    = (ushort*)(ws + 23068672);         //  8,388,608 B
  ushort* Awt   = (ushort*)(ws + 31457280);         //    147,456 B
  float*  Wc    = (float*)(ws + 31604736);          //     16,384 B
  float*  bias2 = (float*)(ws + 31621120);          //        512 B
  float*  biasc = (float*)(ws + 31621632);          //        256 B

  xform_kernel<<<53, 256, 0, stream>>>(enc_w, enc_gamma, enc_var,
                                       comp_w, comp_gamma, comp_var,
                                       enc_b, enc_beta, enc_mean,
                                       comp_beta, comp_mean,
                                       Awt, Wc, bias2, biasc);
  compress_kernel<<<1024, 256, 0, stream>>>(X, Wc, biasc, Wm1t, Xb);
  encode_mfma<<<dim3(16, 16, 4), 256, 0, stream>>>(Wm1t, Awt, bias2, Wtu);
  carafe_kernel<<<dim3(8, 32, 4), 512, 0, stream>>>(Xb, Wtu, out);
}

// Round 12
// 140.690 us; speedup vs baseline: 1.3364x; 1.0370x over previous
//
#include <hip/hip_runtime.h>

#define EPS 1e-5f

typedef __attribute__((ext_vector_type(8))) short short8;
typedef __attribute__((ext_vector_type(4))) float float4v;

__device__ inline unsigned short f2bf(float f) {
  unsigned u = __float_as_uint(f);
  unsigned r = (u + 0x7fffu + ((u >> 16) & 1u)) >> 16;
  return (unsigned short)r;
}
__device__ inline uint pk2(float a, float b) {
  return (uint)f2bf(a) | ((uint)f2bf(b) << 16);
}

// ---------------------------------------------------------------------------
// Measured budget (R10 probe): xform ~3us, compress ~5us, encode ~13us,
// carafe ~24us; ~96us of the window is harness fills + gaps. R11's 16x4
// carafe regressed (more halo overfetch, split weight reads) -> reverted to
// v3. This round's single change: carafe __launch_bounds__(256,2) -> reg cap
// 128 (> ~100 live, no MFMA so no VGPR/AGPR halving) -> 4 waves/EU.
// ---------------------------------------------------------------------------

// ---------------------------------------------------------------------------
// xform: fold BN scale into weights + both bias vectors. (R5 exact)
// ---------------------------------------------------------------------------
__global__ __launch_bounds__(256) void xform_kernel(
    const float* __restrict__ enc_w, const float* __restrict__ enc_gamma,
    const float* __restrict__ enc_var, const float* __restrict__ comp_w,
    const float* __restrict__ comp_gamma, const float* __restrict__ comp_var,
    const float* __restrict__ enc_b, const float* __restrict__ enc_beta,
    const float* __restrict__ enc_mean, const float* __restrict__ comp_beta,
    const float* __restrict__ comp_mean, ushort* __restrict__ Awt,
    float* __restrict__ Wc, float* __restrict__ bias2,
    float* __restrict__ bias_c) {
  int u = blockIdx.x * 256 + threadIdx.x;
  if (u < 9216) {
    int kc = u >> 9, rem = u & 511;
    int mt = rem >> 6, q = (rem >> 4) & 3, ml = rem & 15;
    int e = mt * 16 + ml;
    int t = kc >> 1, h = kc & 1;
    int dy = t / 3, dx = t - dy * 3;
    float inv = (e < 100) ? enc_gamma[e] * rsqrtf(enc_var[e] + EPS) : 0.f;
    ushort o[8];
#pragma unroll
    for (int j = 0; j < 8; ++j) {
      int ci = h * 32 + q * 8 + j;
      float w = (e < 100) ? enc_w[(e * 64 + ci) * 9 + dy * 3 + dx] * inv : 0.f;
      o[j] = f2bf(w);
    }
    uint4 v;
    v.x = (uint)o[0] | ((uint)o[1] << 16);
    v.y = (uint)o[2] | ((uint)o[3] << 16);
    v.z = (uint)o[4] | ((uint)o[5] << 16);
    v.w = (uint)o[6] | ((uint)o[7] << 16);
    *reinterpret_cast<uint4*>(Awt + (size_t)u * 8) = v;
  } else if (u < 13312) {
    int v = u - 9216;
    int co = v & 63;
    float inv = comp_gamma[co] * rsqrtf(comp_var[co] + EPS);
    Wc[v] = comp_w[co * 64 + (v >> 6)] * inv;
  } else if (u < 13440) {
    int t = u - 13312;
    float v = 0.f;
    if (t < 100) {
      float inv = enc_gamma[t] * rsqrtf(enc_var[t] + EPS);
      v = enc_b[t] * inv + enc_beta[t] - enc_mean[t] * inv;
    }
    bias2[t] = v;
  } else if (u < 13504) {
    int c = u - 13440;
    float inv = comp_gamma[c] * rsqrtf(comp_var[c] + EPS);
    bias_c[c] = comp_beta[c] - comp_mean[c] * inv;
  }
}

// ---------------------------------------------------------------------------
// compress: 1x1 conv 64->64 + BN + ReLU -> Wm1t + Xb (bf16 pixel-major).
// (R5 exact)
// ---------------------------------------------------------------------------
__global__ __launch_bounds__(256) void compress_kernel(
    const float* __restrict__ X, const float* __restrict__ Wc,
    const float* __restrict__ bias_c, ushort* __restrict__ out,
    ushort* __restrict__ Xb) {
  __shared__ __align__(16) float xtile[64 * 65];
  __shared__ __align__(16) float osm[64 * 68];
  const int tid = threadIdx.x;
  const int p0 = blockIdx.x * 64;
  const int b = p0 >> 14;
  const float* xbase = X + ((size_t)b << 20) + (p0 & 16383);

#pragma unroll
  for (int k = 0; k < 16; ++k) {
    int u = k * 256 + tid;
    int ci = u >> 6, px = u & 63;      // wave: ci fixed, px 0..63 -> coalesced
    xtile[px * 65 + ci] = xbase[((size_t)ci << 14) + px];
  }
  __syncthreads();

  const int wv = __builtin_amdgcn_readfirstlane(tid >> 6);
  const int ln = tid & 63;
  float acc[16];
#pragma unroll
  for (int u = 0; u < 16; ++u) acc[u] = bias_c[wv * 16 + u];
  const float* xr = xtile + ln * 65;
#pragma unroll 8
  for (int ci = 0; ci < 64; ++ci) {
    float xv = xr[ci];
    const float* wr = Wc + ci * 64 + wv * 16;   // wave-uniform -> s_load
#pragma unroll
    for (int u = 0; u < 16; ++u) acc[u] = fmaf(wr[u], xv, acc[u]);
  }
  float4v* orow = reinterpret_cast<float4v*>(osm) + ln * 17 + wv * 4;
#pragma unroll
  for (int j = 0; j < 4; ++j) {
    float4v t;
#pragma unroll
    for (int s = 0; s < 4; ++s) t[s] = fmaxf(acc[j * 4 + s], 0.f);
    orow[j] = t;                        // stride-17 float4 -> conflict-free
  }
  __syncthreads();

#pragma unroll
  for (int j = 0; j < 2; ++j) {
    int u = j * 256 + tid;
    int px = u >> 3, g = u & 7;
    const float* so = osm + px * 68 + g * 8;
    uint4 vo = make_uint4(pk2(so[0], so[1]), pk2(so[2], so[3]),
                          pk2(so[4], so[5]), pk2(so[6], so[7]));
    *reinterpret_cast<uint4*>(out + (size_t)(p0 + px) * 64 + g * 8) = vo;
    const float* sx = xtile + px * 65 + g * 8;
    uint4 vx = make_uint4(pk2(sx[0], sx[1]), pk2(sx[2], sx[3]),
                          pk2(sx[4], sx[5]), pk2(sx[6], sx[7]));
    *reinterpret_cast<uint4*>(Xb + (size_t)(p0 + px) * 64 + g * 8) = vx;
  }
}

// ---------------------------------------------------------------------------
// encode: 3x3 conv (64->100) implicit GEMM on MFMA + bias + softmax(25) +
// pixel-shuffle de-interleave + bf16 pack -> tile-major Wtu.
// (R5 exact. Measured: ~13us, VGPR=56, MfmaUtil 30%.)
// ---------------------------------------------------------------------------
__global__ __launch_bounds__(256) void encode_mfma(
    const ushort* __restrict__ Wm1t, const ushort* __restrict__ Awt,
    const float* __restrict__ bias2, uint* __restrict__ Wtu) {
  __shared__ __align__(16) char smem[25856];   // Xt 14400 -> wsm 25856 -> wpT
  ushort* Xt = (ushort*)smem;                  // [100 pos (10x10)][72 ci]
  const int tid = threadIdx.x;
  const int b = blockIdx.z;
  const int y0 = blockIdx.y * 8, x0 = blockIdx.x * 8;

  // ---- phase 1: stage compressed features (10x10 halo) ----
  for (int u = tid; u < 800; u += 256) {       // 100 pos x 8 ci-groups
    int pos = u >> 3, cg = u & 7;
    int iy = pos / 10, ix = pos - iy * 10;
    int gy = y0 + iy - 1, gx = x0 + ix - 1;
    uint4 v = make_uint4(0, 0, 0, 0);
    if ((unsigned)gy < 128u && (unsigned)gx < 128u)
      v = *reinterpret_cast<const uint4*>(
          Wm1t + ((((size_t)b << 14) + (gy << 7) + gx) << 6) + cg * 8);
    *reinterpret_cast<uint4*>(&Xt[pos * 72 + cg * 8]) = v;
  }
  __syncthreads();

  // ---- phase 2: implicit-GEMM MFMA over 18 kc slices ----
  const int wave = tid >> 6, lane = tid & 63;
  const int q = lane >> 4, px16 = lane & 15;

  float4v acc[2][4];
#pragma unroll
  for (int a = 0; a < 2; ++a)
#pragma unroll
    for (int n = 0; n < 4; ++n) acc[a][n] = (float4v){0.f, 0.f, 0.f, 0.f};

  const short8* Ap = reinterpret_cast<const short8*>(Awt);
#pragma unroll
  for (int kc = 0; kc < 18; ++kc) {
    const int t = kc >> 1, h = kc & 1;
    const int dy = t / 3, dx = t - dy * 3;
    short8 af[2];
#pragma unroll
    for (int a = 0; a < 2; ++a)
      af[a] = Ap[kc * 512 + (wave * 2 + a) * 64 + lane];
    short8 bfr[4];
#pragma unroll
    for (int n = 0; n < 4; ++n) {
      int p = n * 16 + px16;                  // pixel in 8x8 tile, row-major 8
      int iy = (p >> 3) + dy, ix = (p & 7) + dx;
      bfr[n] = *reinterpret_cast<const short8*>(
          &Xt[(iy * 10 + ix) * 72 + h * 32 + q * 8]);
    }
#pragma unroll
    for (int a = 0; a < 2; ++a)
#pragma unroll
      for (int n = 0; n < 4; ++n)
        acc[a][n] = __builtin_amdgcn_mfma_f32_16x16x32_bf16(
            af[a], bfr[n], acc[a][n], 0, 0, 0);
  }
  __syncthreads();

  // ---- phase 3: accumulators -> wsm [64 px][101] (stride 101 === 5 mod 32,
  // coprime -> phase-4 reads conflict-free; b32 stores) ----
  float* wsm = (float*)smem;
#pragma unroll
  for (int a = 0; a < 2; ++a) {
    int ebase = (wave * 2 + a) * 16 + q * 4;
    if (ebase < 100) {
#pragma unroll
      for (int n = 0; n < 4; ++n) {
        int p = n * 16 + px16;
        float* dst = wsm + p * 101 + ebase;
        dst[0] = acc[a][n][0];
        dst[1] = acc[a][n][1];
        dst[2] = acc[a][n][2];
        dst[3] = acc[a][n][3];
      }
    }
  }
  __syncthreads();

  // ---- phase 4: bias + softmax(25), one (pixel, component) per thread ----
  {
    const int px = tid & 63, qd = tid >> 6;
    const int rowbase = (qd >> 1) * 28;
    const int half = qd & 1;
    const float* wp = wsm + px * 101 + qd;
    float v[25];
#pragma unroll
    for (int j = 0; j < 25; ++j) v[j] = wp[4 * j] + bias2[4 * j + qd];
    float m = v[0];
#pragma unroll
    for (int j = 1; j < 25; ++j) m = fmaxf(m, v[j]);
    float s = 0.f;
#pragma unroll
    for (int j = 0; j < 25; ++j) { v[j] = __expf(v[j] - m); s += v[j]; }
    float inv = 1.f / s;
    __syncthreads();                           // wsm now dead -> reuse as wpT
    ushort* wpS = (ushort*)smem;               // ushort view of wpT [56][128]
#pragma unroll
    for (int k = 0; k < 25; ++k)
      wpS[(rowbase + k) * 128 + px * 2 + half] = f2bf(v[k] * inv);
  }
  __syncthreads();

  // ---- phase 5: stream wpT out, tile-major + coalesced ----
  {
    const uint4* src = (const uint4*)smem;     // wpT [56][64] uint = 896 uint4
    uint4* dst = reinterpret_cast<uint4*>(
        Wtu + (size_t)((b * 16 + blockIdx.y) * 16 + blockIdx.x) * 3584);
    for (int u = tid; u < 896; u += 256) dst[u] = src[u];
  }
}

// ---------------------------------------------------------------------------
// carafe v3 + (256,2): R8-exact body; only change is the launch bound.
// Cap = 256/2 = 128 regs > ~100 live; no MFMA -> no VGPR/AGPR halving ->
// expect VGPR ~100-128, spill-free, 4 waves/EU (2x v3's occupancy).
// ---------------------------------------------------------------------------
__global__ __launch_bounds__(256, 2) void carafe_kernel(
    const ushort* __restrict__ Xb, const uint* __restrict__ Wtu,
    float* __restrict__ out) {
  const int tid = threadIdx.x;
  const int b = blockIdx.z;
  const int y0 = blockIdx.y * 8, x0 = blockIdx.x * 8;
  __shared__ __align__(16) ushort xt[144 * 72];

  for (int u = tid; u < 1152; u += 256) {      // 144 pos x 8 ch-groups
    int pos = u >> 3, cg = u & 7;
    int iy = pos / 12, ix = pos - iy * 12;
    int gy = y0 + iy - 2, gx = x0 + ix - 2;
    uint4 v = make_uint4(0, 0, 0, 0);
    if ((unsigned)gy < 128u && (unsigned)gx < 128u)
      v = *reinterpret_cast<const uint4*>(
          Xb + (((size_t)b * 16384 + gy * 128 + gx) << 6) + cg * 8);
    *reinterpret_cast<uint4*>(&xt[pos * 72 + cg * 8]) = v;
  }
  __syncthreads();

  const int p = tid & 63, cg2 = tid >> 6;      // 16 channels per thread
  const int py = p >> 3, px = p & 7;

  const uint* wt = Wtu +
      (size_t)((b * 16 + blockIdx.y) * 16 + blockIdx.x) * 3584 + p;

  float2 a0[16], a1[16];                       // [ch] x (xq, xq+1), r1=0/1
#pragma unroll
  for (int i = 0; i < 16; ++i) {
    a0[i] = make_float2(0.f, 0.f);
    a1[i] = make_float2(0.f, 0.f);
  }

#pragma unroll
  for (int k = 0; k < 25; ++k) {
    const int dy = k / 5, dx = k - dy * 5;
    const ushort* bp = xt + ((py + dy) * 12 + (px + dx)) * 72 + cg2 * 16;
    uint wk0 = wt[k * 64];                     // r1=0 weights (comp0, comp1)
    uint wk1 = wt[(28 + k) * 64];              // r1=1 weights (comp2, comp3)
    float w00 = __uint_as_float(wk0 << 16);
    float w01 = __uint_as_float(wk0 & 0xffff0000u);
    float w10 = __uint_as_float(wk1 << 16);
    float w11 = __uint_as_float(wk1 & 0xffff0000u);
#pragma unroll
    for (int j = 0; j < 2; ++j) {
      uint4 xv = *reinterpret_cast<const uint4*>(bp + 8 * j);
      const uint xu[4] = {xv.x, xv.y, xv.z, xv.w};
#pragma unroll
      for (int t = 0; t < 4; ++t) {
        float xlo = __uint_as_float(xu[t] << 16);
        float xhi = __uint_as_float(xu[t] & 0xffff0000u);
        int c = j * 8 + t * 2;
        a0[c].x = fmaf(w00, xlo, a0[c].x);
        a0[c].y = fmaf(w01, xlo, a0[c].y);
        a1[c].x = fmaf(w10, xlo, a1[c].x);
        a1[c].y = fmaf(w11, xlo, a1[c].y);
        a0[c + 1].x = fmaf(w00, xhi, a0[c + 1].x);
        a0[c + 1].y = fmaf(w01, xhi, a0[c + 1].y);
        a1[c + 1].x = fmaf(w10, xhi, a1[c + 1].x);
        a1[c + 1].y = fmaf(w11, xhi, a1[c + 1].y);
      }
    }
  }

  const int yq0 = (y0 + py) * 2;
  const int xq = (x0 + px) * 2;
#pragma unroll
  for (int ci = 0; ci < 16; ++ci) {
    int c = cg2 * 16 + ci;
    float* o = out + ((size_t)(b * 64 + c) * 256 + yq0) * 256 + xq;
    *reinterpret_cast<float2*>(o) = a0[ci];        // row yq0   (r1=0)
    *reinterpret_cast<float2*>(o + 256) = a1[ci];  // row yq0+1 (r1=1)
  }
}

// ---------------------------------------------------------------------------
extern "C" void kernel_launch(void* const* d_in, const int* in_sizes, int n_in,
                              void* d_out, int out_size, void* d_ws, size_t ws_size,
                              hipStream_t stream) {
  const float* X          = (const float*)d_in[0];
  const float* comp_w     = (const float*)d_in[1];
  const float* comp_gamma = (const float*)d_in[2];
  const float* comp_beta  = (const float*)d_in[3];
  const float* comp_mean  = (const float*)d_in[4];
  const float* comp_var   = (const float*)d_in[5];
  const float* enc_w      = (const float*)d_in[6];
  const float* enc_b      = (const float*)d_in[7];
  const float* enc_gamma  = (const float*)d_in[8];
  const float* enc_beta   = (const float*)d_in[9];
  const float* enc_mean   = (const float*)d_in[10];
  const float* enc_var    = (const float*)d_in[11];
  float* out = (float*)d_out;

  char* ws = (char*)d_ws;
  ushort* Wm1t  = (ushort*)(ws);                    //  8,388,608 B
  uint*   Wtu   = (uint*)(ws + 8388608);            // 14,680,064 B (tile-major)
  ushort* Xb    = (ushort*)(ws + 23068672);         //  8,388,608 B
  ushort* Awt   = (ushort*)(ws + 31457280);         //    147,456 B
  float*  Wc    = (float*)(ws + 31604736);          //     16,384 B
  float*  bias2 = (float*)(ws + 31621120);          //        512 B
  float*  biasc = (float*)(ws + 31621632);          //        256 B

  xform_kernel<<<53, 256, 0, stream>>>(enc_w, enc_gamma, enc_var,
                                       comp_w, comp_gamma, comp_var,
                                       enc_b, enc_beta, enc_mean,
                                       comp_beta, comp_mean,
                                       Awt, Wc, bias2, biasc);
  compress_kernel<<<1024, 256, 0, stream>>>(X, Wc, biasc, Wm1t, Xb);
  encode_mfma<<<dim3(16, 16, 4), 256, 0, stream>>>(Wm1t, Awt, bias2, Wtu);
  carafe_kernel<<<dim3(16, 16, 4), 256, 0, stream>>>(Xb, Wtu, out);
}